// Round 2
// baseline (257.013 us; speedup 1.0000x reference)
//
#include <hip/hip_runtime.h>

// CRITICAL: the reference's huge outputs come from catastrophic cancellation
// in denom = d00*d11 - d01*d01. numpy rounds each mul/sub separately; FMA
// contraction changes denom by orders of magnitude there. Forbid contraction
// so f32 arithmetic is bitwise-identical to the numpy reference.
#pragma clang fp contract(off)

// Problem constants (match reference)
#define B_ 32
#define H_ 512
#define W_ 384
#define V_ 6890
#define F_ 13776
#define PAD_ 64          // (H - W) / 2
#define WP_ 512          // W + 2*PAD

// ---------------------------------------------------------------------------
// Kernel 1: build vf2[b][f] = "face f seen by any pixel of view-2 in batch b"
// Plain byte stores (idempotent OR), no atomics needed.
// ---------------------------------------------------------------------------
__global__ __launch_bounds__(256) void vf2_scatter_kernel(
    const int* __restrict__ vis_2, unsigned char* __restrict__ vf2)
{
    int idx = blockIdx.x * blockDim.x + threadIdx.x;
    const int total = B_ * H_ * W_;
    if (idx >= total) return;
    int v = vis_2[idx];
    if (v >= 0) {
        int b = idx / (H_ * W_);
        vf2[b * F_ + v] = 1;
    }
}

// ---------------------------------------------------------------------------
// Kernel 2: per-pixel flow grid + mask over the PADDED output (B,H,WP).
// out_grid: (B,H,WP,2) f32, corr_mask: (B,H,WP,1) f32, concatenated in d_out.
// Every f32 op mirrors the reference's op order exactly (no contraction).
// ---------------------------------------------------------------------------
__global__ __launch_bounds__(256) void flow_main_kernel(
    const float* __restrict__ verts_1,
    const int*   __restrict__ vis_1,
    const float* __restrict__ verts_2,
    const int*   __restrict__ face,
    const float* __restrict__ vis_sym_mask_1,
    const int*   __restrict__ symtab,
    const unsigned char* __restrict__ vf2,
    float* __restrict__ out_grid,    // B*H*WP*2 floats
    float* __restrict__ corr_mask)   // B*H*WP floats
{
#pragma clang fp contract(off)
    int idx = blockIdx.x * blockDim.x + threadIdx.x;
    const int total = B_ * H_ * WP_;
    if (idx >= total) return;

    int xp  = idx % WP_;
    int rem = idx / WP_;      // b*H + y
    int y   = rem % H_;
    int b   = rem / H_;

    float2* og = reinterpret_cast<float2*>(out_grid);

    if (xp < PAD_ || xp >= W_ + PAD_) {
        // padded corr = 0 exactly -> flow = -base, grid = 0 -> gx = gy = -1
        og[idx] = make_float2(-1.0f, -1.0f);
        corr_mask[idx] = 2.0f;
        return;
    }

    int x   = xp - PAD_;
    int pin = (b * H_ + y) * W_ + x;

    int  vis1 = vis_1[pin];
    bool bg   = vis1 < 0;
    int  fc   = bg ? 0 : vis1;

    int i0 = face[fc * 3 + 0];
    int i1 = face[fc * 3 + 1];
    int i2 = face[fc * 3 + 2];

    const float* v1b = verts_1 + (size_t)b * (V_ * 3);
    float ax = v1b[i0 * 3 + 0], ay = v1b[i0 * 3 + 1];
    float bx = v1b[i1 * 3 + 0], by = v1b[i1 * 3 + 1];
    float cx = v1b[i2 * 3 + 0], cy = v1b[i2 * 3 + 1];

    float px = (float)x, py = (float)y;

    float e0x = bx - ax, e0y = by - ay;
    float e1x = cx - ax, e1y = cy - ay;
    float e2x = px - ax, e2y = py - ay;

    // (e*e).sum(-1): mul, mul, add — each individually rounded
    float d00 = (e0x * e0x) + (e0y * e0y);
    float d01 = (e0x * e1x) + (e0y * e1y);
    float d11 = (e1x * e1x) + (e1y * e1y);
    float d20 = (e2x * e0x) + (e2y * e0y);
    float d21 = (e2x * e1x) + (e2y * e1y);

    float denom = (d00 * d11) - (d01 * d01);
    if (fabsf(denom) < 1e-12f) denom = 1.0f;

    float wv = ((d11 * d20) - (d01 * d21)) / denom;
    float ww = ((d00 * d21) - (d01 * d20)) / denom;
    float w0 = (1.0f - wv) - ww;   // numpy: (1.0 - wv) - ww

    bool vis2f = vf2[b * F_ + fc] != 0;

    int s0 = symtab[i0], s1 = symtab[i1], s2 = symtab[i2];
    float msk = vis_sym_mask_1[pin];
    bool sym_ok  = (s0 >= 0) && (s1 >= 0) && (s2 >= 0) && (msk > 0.0f);
    bool use_sym = (!vis2f) && sym_ok && (!bg);

    int t0 = use_sym ? s0 : i0;
    int t1 = use_sym ? s1 : i1;
    int t2 = use_sym ? s2 : i2;

    const float* v2b = verts_2 + (size_t)b * (V_ * 3);
    float q0x = v2b[t0 * 3 + 0], q0y = v2b[t0 * 3 + 1];
    float q1x = v2b[t1 * 3 + 0], q1y = v2b[t1 * 3 + 1];
    float q2x = v2b[t2 * 3 + 0], q2y = v2b[t2 * 3 + 1];

    // einsum: sequential sum over k = 0,1,2
    float corr_x = ((w0 * q0x) + (wv * q1x)) + (ww * q2x);
    float corr_y = ((w0 * q0y) + (wv * q1y)) + (ww * q2y);

    bool has_corr = (!bg) && (vis2f || use_sym);
    if (!has_corr) { corr_x = 0.0f; corr_y = 0.0f; }

    corr_x = corr_x + (float)PAD_;   // reference: corr + [pad, 0]

    // Replicate flow = corr - base; grid = base + flow (extra roundings!)
    float base_x = (float)xp, base_y = (float)y;
    float fx = corr_x - base_x;
    float fy = corr_y - base_y;
    float gxv = base_x + fx;
    float gyv = base_y + fy;

    // gx = 2*grid/ (Wp-1) - 1, op order: mul, div, sub
    float gx = ((2.0f * gxv) / (float)(WP_ - 1)) - 1.0f;
    float gy = ((2.0f * gyv) / (float)(H_  - 1)) - 1.0f;

    og[idx] = make_float2(gx, gy);
    corr_mask[idx] = bg ? 2.0f : (has_corr ? 0.0f : 1.0f);
}

extern "C" void kernel_launch(void* const* d_in, const int* in_sizes, int n_in,
                              void* d_out, int out_size, void* d_ws, size_t ws_size,
                              hipStream_t stream)
{
    // setup_inputs() order:
    // 0: verts_1 (B,V,3) f32
    // 1: vis_1   (B,H,W) i32
    // 2: verts_2 (B,V,3) f32
    // 3: vis_2   (B,H,W) i32
    // 4: face    (F,3)   i32
    // 5: vis_sym_mask_1 (B,H,W) f32
    // 6: symmetric_table (V+1,) i32
    const float* verts_1 = (const float*)d_in[0];
    const int*   vis_1   = (const int*)d_in[1];
    const float* verts_2 = (const float*)d_in[2];
    const int*   vis_2   = (const int*)d_in[3];
    const int*   face    = (const int*)d_in[4];
    const float* vis_sym = (const float*)d_in[5];
    const int*   symtab  = (const int*)d_in[6];

    float* out_grid  = (float*)d_out;                              // B*H*WP*2
    float* corr_mask = (float*)d_out + (size_t)B_ * H_ * WP_ * 2;  // B*H*WP

    unsigned char* vf2 = (unsigned char*)d_ws;                     // B*F bytes

    // zero the visibility table each call (deterministic, graph-capturable)
    hipMemsetAsync(vf2, 0, (size_t)B_ * F_, stream);

    {
        const int total = B_ * H_ * W_;
        const int block = 256;
        const int grid  = (total + block - 1) / block;
        vf2_scatter_kernel<<<grid, block, 0, stream>>>(vis_2, vf2);
    }
    {
        const int total = B_ * H_ * WP_;
        const int block = 256;
        const int grid  = (total + block - 1) / block;
        flow_main_kernel<<<grid, block, 0, stream>>>(
            verts_1, vis_1, verts_2, face, vis_sym, symtab, vf2,
            out_grid, corr_mask);
    }
}

// Round 3
// 117.653 us; speedup vs baseline: 2.1845x; 2.1845x over previous
//
#include <hip/hip_runtime.h>

// Forbid FP contraction everywhere: the reference's huge outputs come from
// catastrophic cancellation (denom = d00*d11 - d01*d01); FMA contraction
// changes those bits by orders of magnitude. All f32 ops must round exactly
// like numpy's.
#pragma clang fp contract(off)

#define B_ 32
#define H_ 512
#define W_ 384
#define V_ 6890
#define F_ 13776
#define PAD_ 64          // (H - W) / 2
#define WP_ 512          // W + 2*PAD

// Per-(b,f) record: exactly 64 bytes = one cache line.
// w0: [ax, ay, e0x, e0y]
// w1: [e1x, e1y, d00(sign=vis2f), d01]
// w2: [d11(sign=sym_ok), denom, q0x, q0y]
// w3: [q1x, q1y, q2x, q2y]
// d00,d11 >= 0 always, so their sign bits are free flag storage.

// ---------------------------------------------------------------------------
// Kernel 1: vf2[b][f] = any view-2 pixel sees face f (idempotent byte OR).
// ---------------------------------------------------------------------------
__global__ __launch_bounds__(256) void vf2_scatter_kernel(
    const int* __restrict__ vis_2, unsigned char* __restrict__ vf2)
{
    int idx = blockIdx.x * blockDim.x + threadIdx.x;
    const int total = B_ * H_ * W_;
    if (idx >= total) return;
    int v = vis_2[idx];
    if (v >= 0) {
        int b = idx / (H_ * W_);
        vf2[b * F_ + v] = 1;
    }
}

// ---------------------------------------------------------------------------
// Kernel 2: build the per-(b,f) 64B records. One thread per (b,f).
// Gathers hit small L2-resident tables; face/vf2 reads and record writes
// are coalesced.
// ---------------------------------------------------------------------------
__global__ __launch_bounds__(256) void face_precompute_kernel(
    const float* __restrict__ verts_1,
    const float* __restrict__ verts_2,
    const int*   __restrict__ face,
    const int*   __restrict__ symtab,
    const unsigned char* __restrict__ vf2,
    float4* __restrict__ recs)            // B*F*4 float4s
{
#pragma clang fp contract(off)
    int idx = blockIdx.x * blockDim.x + threadIdx.x;
    const int total = B_ * F_;
    if (idx >= total) return;
    int f = idx % F_;
    int b = idx / F_;

    int i0 = face[f * 3 + 0];
    int i1 = face[f * 3 + 1];
    int i2 = face[f * 3 + 2];

    const float* v1b = verts_1 + (size_t)b * (V_ * 3);
    float ax = v1b[i0 * 3 + 0], ay = v1b[i0 * 3 + 1];
    float bx = v1b[i1 * 3 + 0], by = v1b[i1 * 3 + 1];
    float cx = v1b[i2 * 3 + 0], cy = v1b[i2 * 3 + 1];

    float e0x = bx - ax, e0y = by - ay;
    float e1x = cx - ax, e1y = cy - ay;

    float d00 = (e0x * e0x) + (e0y * e0y);
    float d01 = (e0x * e1x) + (e0y * e1y);
    float d11 = (e1x * e1x) + (e1y * e1y);

    float denom = (d00 * d11) - (d01 * d01);
    if (fabsf(denom) < 1e-12f) denom = 1.0f;

    bool vis2f = vf2[idx] != 0;

    int s0 = symtab[i0], s1 = symtab[i1], s2 = symtab[i2];
    bool sym_ok = (s0 >= 0) && (s1 >= 0) && (s2 >= 0);

    // Select the verts_2 triangle that a has_corr pixel would use:
    // vis2f -> tri; else (sym_ok) -> sym_tri; else unused (corr forced to 0).
    int t0 = (!vis2f && sym_ok) ? s0 : i0;
    int t1 = (!vis2f && sym_ok) ? s1 : i1;
    int t2 = (!vis2f && sym_ok) ? s2 : i2;

    const float* v2b = verts_2 + (size_t)b * (V_ * 3);
    float q0x = v2b[t0 * 3 + 0], q0y = v2b[t0 * 3 + 1];
    float q1x = v2b[t1 * 3 + 0], q1y = v2b[t1 * 3 + 1];
    float q2x = v2b[t2 * 3 + 0], q2y = v2b[t2 * 3 + 1];

    // Pack flags into sign bits of the nonnegative d00 / d11.
    unsigned u00 = __float_as_uint(d00) | (vis2f  ? 0x80000000u : 0u);
    unsigned u11 = __float_as_uint(d11) | (sym_ok ? 0x80000000u : 0u);

    float4* r = recs + (size_t)idx * 4;
    r[0] = make_float4(ax, ay, e0x, e0y);
    r[1] = make_float4(e1x, e1y, __uint_as_float(u00), d01);
    r[2] = make_float4(__uint_as_float(u11), denom, q0x, q0y);
    r[3] = make_float4(q1x, q1y, q2x, q2y);
}

// ---------------------------------------------------------------------------
// Kernel 3: per-pixel main over the PADDED grid. One random 64B record load
// per pixel; everything else coalesced.
// ---------------------------------------------------------------------------
__global__ __launch_bounds__(256) void flow_main_kernel(
    const int*   __restrict__ vis_1,
    const float* __restrict__ vis_sym_mask_1,
    const float4* __restrict__ recs,
    float* __restrict__ out_grid,    // B*H*WP*2 floats
    float* __restrict__ corr_mask)   // B*H*WP floats
{
#pragma clang fp contract(off)
    int idx = blockIdx.x * blockDim.x + threadIdx.x;
    const int total = B_ * H_ * WP_;
    if (idx >= total) return;

    int xp  = idx % WP_;
    int rem = idx / WP_;      // b*H + y
    int y   = rem % H_;
    int b   = rem / H_;

    float2* og = reinterpret_cast<float2*>(out_grid);

    if (xp < PAD_ || xp >= W_ + PAD_) {
        og[idx] = make_float2(-1.0f, -1.0f);
        corr_mask[idx] = 2.0f;
        return;
    }

    int x   = xp - PAD_;
    int pin = (b * H_ + y) * W_ + x;

    int  vis1 = vis_1[pin];
    float msk = vis_sym_mask_1[pin];
    bool bg   = vis1 < 0;
    int  fc   = bg ? 0 : vis1;

    const float4* r = recs + ((size_t)b * F_ + fc) * 4;
    float4 w0v = r[0];
    float4 w1v = r[1];
    float4 w2v = r[2];
    float4 w3v = r[3];

    float ax = w0v.x, ay = w0v.y, e0x = w0v.z, e0y = w0v.w;
    float e1x = w1v.x, e1y = w1v.y;
    unsigned u00 = __float_as_uint(w1v.z);
    float d01 = w1v.w;
    unsigned u11 = __float_as_uint(w2v.x);
    float denom = w2v.y;
    float q0x = w2v.z, q0y = w2v.w;
    float q1x = w3v.x, q1y = w3v.y, q2x = w3v.z, q2y = w3v.w;

    bool vis2f  = (u00 >> 31) != 0;
    bool sym_ok = (u11 >> 31) != 0;
    float d00 = __uint_as_float(u00 & 0x7fffffffu);
    float d11 = __uint_as_float(u11 & 0x7fffffffu);

    float px = (float)x, py = (float)y;
    float e2x = px - ax, e2y = py - ay;

    float d20 = (e2x * e0x) + (e2y * e0y);
    float d21 = (e2x * e1x) + (e2y * e1y);

    float wv = ((d11 * d20) - (d01 * d21)) / denom;
    float ww = ((d00 * d21) - (d01 * d20)) / denom;
    float w0 = (1.0f - wv) - ww;

    bool use_sym  = (!vis2f) && sym_ok && (msk > 0.0f) && (!bg);
    bool has_corr = (!bg) && (vis2f || use_sym);

    float corr_x = ((w0 * q0x) + (wv * q1x)) + (ww * q2x);
    float corr_y = ((w0 * q0y) + (wv * q1y)) + (ww * q2y);
    if (!has_corr) { corr_x = 0.0f; corr_y = 0.0f; }

    corr_x = corr_x + (float)PAD_;

    // Replicate flow = corr - base; grid = base + flow (extra roundings).
    float base_x = (float)xp, base_y = (float)y;
    float fx = corr_x - base_x;
    float fy = corr_y - base_y;
    float gxv = base_x + fx;
    float gyv = base_y + fy;

    float gx = ((2.0f * gxv) / (float)(WP_ - 1)) - 1.0f;
    float gy = ((2.0f * gyv) / (float)(H_  - 1)) - 1.0f;

    og[idx] = make_float2(gx, gy);
    corr_mask[idx] = bg ? 2.0f : (has_corr ? 0.0f : 1.0f);
}

extern "C" void kernel_launch(void* const* d_in, const int* in_sizes, int n_in,
                              void* d_out, int out_size, void* d_ws, size_t ws_size,
                              hipStream_t stream)
{
    const float* verts_1 = (const float*)d_in[0];
    const int*   vis_1   = (const int*)d_in[1];
    const float* verts_2 = (const float*)d_in[2];
    const int*   vis_2   = (const int*)d_in[3];
    const int*   face    = (const int*)d_in[4];
    const float* vis_sym = (const float*)d_in[5];
    const int*   symtab  = (const int*)d_in[6];

    float* out_grid  = (float*)d_out;                              // B*H*WP*2
    float* corr_mask = (float*)d_out + (size_t)B_ * H_ * WP_ * 2;  // B*H*WP

    // Workspace layout: [vf2: B*F bytes][align 64][recs: B*F*64 bytes]
    unsigned char* vf2 = (unsigned char*)d_ws;
    size_t rec_off = ((size_t)B_ * F_ + 63) & ~(size_t)63;
    float4* recs = (float4*)((unsigned char*)d_ws + rec_off);

    hipMemsetAsync(vf2, 0, (size_t)B_ * F_, stream);

    {
        const int total = B_ * H_ * W_;
        const int block = 256;
        vf2_scatter_kernel<<<(total + block - 1) / block, block, 0, stream>>>(
            vis_2, vf2);
    }
    {
        const int total = B_ * F_;
        const int block = 256;
        face_precompute_kernel<<<(total + block - 1) / block, block, 0, stream>>>(
            verts_1, verts_2, face, symtab, vf2, recs);
    }
    {
        const int total = B_ * H_ * WP_;
        const int block = 256;
        flow_main_kernel<<<(total + block - 1) / block, block, 0, stream>>>(
            vis_1, vis_sym, recs, out_grid, corr_mask);
    }
}

// Round 4
// 110.610 us; speedup vs baseline: 2.3236x; 1.0637x over previous
//
#include <hip/hip_runtime.h>

// Forbid FP contraction everywhere: the reference's huge outputs come from
// catastrophic cancellation (denom = d00*d11 - d01*d01); FMA contraction
// changes those bits by orders of magnitude. All f32 ops must round exactly
// like numpy's.
#pragma clang fp contract(off)

#define B_ 32
#define H_ 512
#define W_ 384
#define V_ 6890
#define F_ 13776
#define PAD_ 64          // (H - W) / 2
#define WP_ 512          // W + 2*PAD
#define NXCD_ 8

// Per-(b,f) record: exactly 64 bytes = one cache line.
// w0: [ax, ay, e0x, e0y]
// w1: [e1x, e1y, d00(sign=vis2f), d01]
// w2: [d11(sign=sym_ok), denom, q0x, q0y]
// w3: [q1x, q1y, q2x, q2y]

// ---------------------------------------------------------------------------
// Kernel 1: vf2[b][f] = any view-2 pixel sees face f. int4-vectorized reads,
// idempotent byte stores (no atomics needed). XCD-chunk swizzled.
// ---------------------------------------------------------------------------
__global__ __launch_bounds__(256) void vf2_scatter_kernel(
    const int4* __restrict__ vis_2_v4, unsigned char* __restrict__ vf2)
{
    unsigned bid = blockIdx.x;
    unsigned cpx = gridDim.x >> 3;                 // gridDim divisible by 8
    unsigned swz = (bid & 7u) * cpx + (bid >> 3);
    int idx = (int)(swz * blockDim.x + threadIdx.x);
    const int total4 = B_ * H_ * W_ / 4;
    if (idx >= total4) return;
    int4 v = vis_2_v4[idx];
    int b = idx / (H_ * W_ / 4);                   // 4-px groups never cross b
    unsigned char* t = vf2 + (size_t)b * F_;
    if (v.x >= 0) t[v.x] = 1;
    if (v.y >= 0) t[v.y] = 1;
    if (v.z >= 0) t[v.z] = 1;
    if (v.w >= 0) t[v.w] = 1;
}

// ---------------------------------------------------------------------------
// Kernel 2: build the per-(b,f) 64B records. One thread per (b,f).
// ---------------------------------------------------------------------------
__global__ __launch_bounds__(256) void face_precompute_kernel(
    const float* __restrict__ verts_1,
    const float* __restrict__ verts_2,
    const int*   __restrict__ face,
    const int*   __restrict__ symtab,
    const unsigned char* __restrict__ vf2,
    float4* __restrict__ recs)            // B*F*4 float4s
{
#pragma clang fp contract(off)
    int idx = blockIdx.x * blockDim.x + threadIdx.x;
    const int total = B_ * F_;
    if (idx >= total) return;
    int f = idx % F_;
    int b = idx / F_;

    int i0 = face[f * 3 + 0];
    int i1 = face[f * 3 + 1];
    int i2 = face[f * 3 + 2];

    const float* v1b = verts_1 + (size_t)b * (V_ * 3);
    float ax = v1b[i0 * 3 + 0], ay = v1b[i0 * 3 + 1];
    float bx = v1b[i1 * 3 + 0], by = v1b[i1 * 3 + 1];
    float cx = v1b[i2 * 3 + 0], cy = v1b[i2 * 3 + 1];

    float e0x = bx - ax, e0y = by - ay;
    float e1x = cx - ax, e1y = cy - ay;

    float d00 = (e0x * e0x) + (e0y * e0y);
    float d01 = (e0x * e1x) + (e0y * e1y);
    float d11 = (e1x * e1x) + (e1y * e1y);

    float denom = (d00 * d11) - (d01 * d01);
    if (fabsf(denom) < 1e-12f) denom = 1.0f;

    bool vis2f = vf2[idx] != 0;

    int s0 = symtab[i0], s1 = symtab[i1], s2 = symtab[i2];
    bool sym_ok = (s0 >= 0) && (s1 >= 0) && (s2 >= 0);

    int t0 = (!vis2f && sym_ok) ? s0 : i0;
    int t1 = (!vis2f && sym_ok) ? s1 : i1;
    int t2 = (!vis2f && sym_ok) ? s2 : i2;

    const float* v2b = verts_2 + (size_t)b * (V_ * 3);
    float q0x = v2b[t0 * 3 + 0], q0y = v2b[t0 * 3 + 1];
    float q1x = v2b[t1 * 3 + 0], q1y = v2b[t1 * 3 + 1];
    float q2x = v2b[t2 * 3 + 0], q2y = v2b[t2 * 3 + 1];

    unsigned u00 = __float_as_uint(d00) | (vis2f  ? 0x80000000u : 0u);
    unsigned u11 = __float_as_uint(d11) | (sym_ok ? 0x80000000u : 0u);

    float4* r = recs + (size_t)idx * 4;
    r[0] = make_float4(ax, ay, e0x, e0y);
    r[1] = make_float4(e1x, e1y, __uint_as_float(u00), d01);
    r[2] = make_float4(__uint_as_float(u11), denom, q0x, q0y);
    r[3] = make_float4(q1x, q1y, q2x, q2y);
}

// ---------------------------------------------------------------------------
// Kernel 3: per-pixel main over the PADDED grid, 2 adjacent pixels/thread.
// XCD-chunk swizzled so each XCD's recs working set is ~1 batch (880 KB).
// Pairs never straddle the pad/interior boundary (PAD_ and W_+PAD_ even).
// ---------------------------------------------------------------------------
__global__ __launch_bounds__(256) void flow_main_kernel(
    const int*   __restrict__ vis_1,
    const float* __restrict__ vis_sym_mask_1,
    const float4* __restrict__ recs,
    float* __restrict__ out_grid,    // B*H*WP*2 floats
    float* __restrict__ corr_mask)   // B*H*WP floats
{
#pragma clang fp contract(off)
    unsigned bid = blockIdx.x;
    unsigned cpx = gridDim.x >> 3;                 // 16384/8 = 2048
    unsigned swz = (bid & 7u) * cpx + (bid >> 3);
    int tid  = (int)(swz * blockDim.x + threadIdx.x);
    int base = tid * 2;                            // first of 2 adjacent px
    const int total = B_ * H_ * WP_;
    if (base >= total) return;

    int xp  = base % WP_;          // even
    int rem = base / WP_;          // b*H + y
    int y   = rem % H_;
    int b   = rem / H_;

    if (xp < PAD_ || xp >= W_ + PAD_) {
        reinterpret_cast<float4*>(out_grid)[base >> 1] =
            make_float4(-1.0f, -1.0f, -1.0f, -1.0f);
        reinterpret_cast<float2*>(corr_mask)[base >> 1] =
            make_float2(2.0f, 2.0f);
        return;
    }

    int x   = xp - PAD_;
    int pin = (b * H_ + y) * W_ + x;

    int2   vv = *reinterpret_cast<const int2*>(vis_1 + pin);
    float2 mm = *reinterpret_cast<const float2*>(vis_sym_mask_1 + pin);

    int   vis[2] = { vv.x, vv.y };
    float msk[2] = { mm.x, mm.y };

    // Issue all 8 record loads up front (2 independent gather chains).
    float4 R[2][4];
    bool   bgs[2];
    #pragma unroll
    for (int k = 0; k < 2; ++k) {
        bgs[k] = vis[k] < 0;
        int fc = bgs[k] ? 0 : vis[k];
        const float4* r = recs + ((size_t)b * F_ + fc) * 4;
        R[k][0] = r[0]; R[k][1] = r[1]; R[k][2] = r[2]; R[k][3] = r[3];
    }

    float gxo[2], gyo[2], cmo[2];
    #pragma unroll
    for (int k = 0; k < 2; ++k) {
        float ax = R[k][0].x, ay = R[k][0].y, e0x = R[k][0].z, e0y = R[k][0].w;
        float e1x = R[k][1].x, e1y = R[k][1].y;
        unsigned u00 = __float_as_uint(R[k][1].z);
        float d01 = R[k][1].w;
        unsigned u11 = __float_as_uint(R[k][2].x);
        float denom = R[k][2].y;
        float q0x = R[k][2].z, q0y = R[k][2].w;
        float q1x = R[k][3].x, q1y = R[k][3].y, q2x = R[k][3].z, q2y = R[k][3].w;

        bool vis2f  = (u00 >> 31) != 0;
        bool sym_ok = (u11 >> 31) != 0;
        float d00 = __uint_as_float(u00 & 0x7fffffffu);
        float d11 = __uint_as_float(u11 & 0x7fffffffu);

        float px = (float)(x + k), py = (float)y;
        float e2x = px - ax, e2y = py - ay;

        float d20 = (e2x * e0x) + (e2y * e0y);
        float d21 = (e2x * e1x) + (e2y * e1y);

        float wv = ((d11 * d20) - (d01 * d21)) / denom;
        float ww = ((d00 * d21) - (d01 * d20)) / denom;
        float w0 = (1.0f - wv) - ww;

        bool bg = bgs[k];
        bool use_sym  = (!vis2f) && sym_ok && (msk[k] > 0.0f) && (!bg);
        bool has_corr = (!bg) && (vis2f || use_sym);

        float corr_x = ((w0 * q0x) + (wv * q1x)) + (ww * q2x);
        float corr_y = ((w0 * q0y) + (wv * q1y)) + (ww * q2y);
        if (!has_corr) { corr_x = 0.0f; corr_y = 0.0f; }

        corr_x = corr_x + (float)PAD_;

        // Replicate flow = corr - base; grid = base + flow (extra roundings).
        float base_x = (float)(xp + k), base_y = (float)y;
        float fx = corr_x - base_x;
        float fy = corr_y - base_y;
        float gxv = base_x + fx;
        float gyv = base_y + fy;

        gxo[k] = ((2.0f * gxv) / (float)(WP_ - 1)) - 1.0f;
        gyo[k] = ((2.0f * gyv) / (float)(H_  - 1)) - 1.0f;
        cmo[k] = bg ? 2.0f : (has_corr ? 0.0f : 1.0f);
    }

    reinterpret_cast<float4*>(out_grid)[base >> 1] =
        make_float4(gxo[0], gyo[0], gxo[1], gyo[1]);
    reinterpret_cast<float2*>(corr_mask)[base >> 1] =
        make_float2(cmo[0], cmo[1]);
}

extern "C" void kernel_launch(void* const* d_in, const int* in_sizes, int n_in,
                              void* d_out, int out_size, void* d_ws, size_t ws_size,
                              hipStream_t stream)
{
    const float* verts_1 = (const float*)d_in[0];
    const int*   vis_1   = (const int*)d_in[1];
    const float* verts_2 = (const float*)d_in[2];
    const int*   vis_2   = (const int*)d_in[3];
    const int*   face    = (const int*)d_in[4];
    const float* vis_sym = (const float*)d_in[5];
    const int*   symtab  = (const int*)d_in[6];

    float* out_grid  = (float*)d_out;                              // B*H*WP*2
    float* corr_mask = (float*)d_out + (size_t)B_ * H_ * WP_ * 2;  // B*H*WP

    // Workspace layout: [vf2: B*F bytes][align 64][recs: B*F*64 bytes]
    unsigned char* vf2 = (unsigned char*)d_ws;
    size_t rec_off = ((size_t)B_ * F_ + 63) & ~(size_t)63;
    float4* recs = (float4*)((unsigned char*)d_ws + rec_off);

    hipMemsetAsync(vf2, 0, (size_t)B_ * F_, stream);

    {
        const int total4 = B_ * H_ * W_ / 4;          // 1572864
        const int block  = 256;
        const int grid   = total4 / block;            // 6144, %8 == 0
        vf2_scatter_kernel<<<grid, block, 0, stream>>>(
            (const int4*)vis_2, vf2);
    }
    {
        const int total = B_ * F_;
        const int block = 256;
        face_precompute_kernel<<<(total + block - 1) / block, block, 0, stream>>>(
            verts_1, verts_2, face, symtab, vf2, recs);
    }
    {
        const int total = B_ * H_ * WP_;              // 8388608
        const int block = 256;
        const int grid  = total / (block * 2);        // 16384, %8 == 0
        flow_main_kernel<<<grid, block, 0, stream>>>(
            vis_1, vis_sym, recs, out_grid, corr_mask);
    }
}

// Round 5
// 94.657 us; speedup vs baseline: 2.7152x; 1.1685x over previous
//
#include <hip/hip_runtime.h>

// f32 parts that must be bit-exact vs numpy (denom chain, clamps) forbid FMA
// contraction. The affine-coefficient algebra is done in f64 and rounded once.
#pragma clang fp contract(off)

#define B_ 32
#define H_ 512
#define W_ 384
#define V_ 6890
#define F_ 13776
#define PAD_ 64          // (H - W) / 2
#define WP_ 512          // W + 2*PAD

// Per-(b,f) record: 32 bytes (2 records per 64B line).
// r0: [A'x, Bx, Cx, A'y]   corr_x = A'x + px*Bx + py*Cx
// r1: [By, Cy, flags, 0]   corr_y = A'y + px*By + py*Cy
// flags bit0 = vis2f, bit1 = sym_ok.

// ---------------------------------------------------------------------------
// Kernel 1: vf2[b][f] = any view-2 pixel sees face f. int4 reads, idempotent
// byte stores. XCD-chunk swizzled.
// ---------------------------------------------------------------------------
__global__ __launch_bounds__(256) void vf2_scatter_kernel(
    const int4* __restrict__ vis_2_v4, unsigned char* __restrict__ vf2)
{
    unsigned bid = blockIdx.x;
    unsigned cpx = gridDim.x >> 3;                 // gridDim divisible by 8
    unsigned swz = (bid & 7u) * cpx + (bid >> 3);
    int idx = (int)(swz * blockDim.x + threadIdx.x);
    const int total4 = B_ * H_ * W_ / 4;
    if (idx >= total4) return;
    int4 v = vis_2_v4[idx];
    int b = idx / (H_ * W_ / 4);                   // groups never cross b
    unsigned char* t = vf2 + (size_t)b * F_;
    if (v.x >= 0) t[v.x] = 1;
    if (v.y >= 0) t[v.y] = 1;
    if (v.z >= 0) t[v.z] = 1;
    if (v.w >= 0) t[v.w] = 1;
}

// ---------------------------------------------------------------------------
// Kernel 2: build 32B affine records. denom/flags bit-exact in f32 (ref op
// order); coefficient algebra in f64, rounded once to f32.
// ---------------------------------------------------------------------------
__global__ __launch_bounds__(256) void face_precompute_kernel(
    const float* __restrict__ verts_1,
    const float* __restrict__ verts_2,
    const int*   __restrict__ face,
    const int*   __restrict__ symtab,
    const unsigned char* __restrict__ vf2,
    float4* __restrict__ recs)            // B*F*2 float4s
{
#pragma clang fp contract(off)
    int idx = blockIdx.x * blockDim.x + threadIdx.x;
    const int total = B_ * F_;
    if (idx >= total) return;
    int f = idx % F_;
    int b = idx / F_;

    int i0 = face[f * 3 + 0];
    int i1 = face[f * 3 + 1];
    int i2 = face[f * 3 + 2];

    const float* v1b = verts_1 + (size_t)b * (V_ * 3);
    float ax = v1b[i0 * 3 + 0], ay = v1b[i0 * 3 + 1];
    float bx = v1b[i1 * 3 + 0], by = v1b[i1 * 3 + 1];
    float cx = v1b[i2 * 3 + 0], cy = v1b[i2 * 3 + 1];

    // f32, exact reference op order (these feed the denom clamp decision).
    float e0x = bx - ax, e0y = by - ay;
    float e1x = cx - ax, e1y = cy - ay;
    float d00 = (e0x * e0x) + (e0y * e0y);
    float d01 = (e0x * e1x) + (e0y * e1y);
    float d11 = (e1x * e1x) + (e1y * e1y);
    float denom = (d00 * d11) - (d01 * d01);
    if (fabsf(denom) < 1e-12f) denom = 1.0f;

    bool vis2f = vf2[idx] != 0;
    int s0 = symtab[i0], s1 = symtab[i1], s2 = symtab[i2];
    bool sym_ok = (s0 >= 0) && (s1 >= 0) && (s2 >= 0);

    int t0 = (!vis2f && sym_ok) ? s0 : i0;
    int t1 = (!vis2f && sym_ok) ? s1 : i1;
    int t2 = (!vis2f && sym_ok) ? s2 : i2;

    const float* v2b = verts_2 + (size_t)b * (V_ * 3);
    float q0x = v2b[t0 * 3 + 0], q0y = v2b[t0 * 3 + 1];
    float q1x = v2b[t1 * 3 + 0], q1y = v2b[t1 * 3 + 1];
    float q2x = v2b[t2 * 3 + 0], q2y = v2b[t2 * 3 + 1];

    // f64 affine algebra:
    // wv = e2 . U, ww = e2 . Vv; corr = q0 + wv*(q1-q0) + ww*(q2-q0)
    // corr_x = A'x + px*Bx + py*Cx  (e2 = p - a folded into A')
    double dd00 = (double)d00, dd01 = (double)d01, dd11 = (double)d11;
    double dden = (double)denom;
    double De0x = (double)e0x, De0y = (double)e0y;
    double De1x = (double)e1x, De1y = (double)e1y;

    double Ux = (dd11 * De0x - dd01 * De1x) / dden;
    double Uy = (dd11 * De0y - dd01 * De1y) / dden;
    double Vx = (dd00 * De1x - dd01 * De0x) / dden;
    double Vy = (dd00 * De1y - dd01 * De0y) / dden;

    double dq1x = (double)q1x - (double)q0x;
    double dq2x = (double)q2x - (double)q0x;
    double dq1y = (double)q1y - (double)q0y;
    double dq2y = (double)q2y - (double)q0y;

    double Bx = Ux * dq1x + Vx * dq2x;
    double Cx = Uy * dq1x + Vy * dq2x;
    double By = Ux * dq1y + Vx * dq2y;
    double Cy = Uy * dq1y + Vy * dq2y;

    double Apx = (double)q0x - (double)ax * Bx - (double)ay * Cx;
    double Apy = (double)q0y - (double)ax * By - (double)ay * Cy;

    unsigned flags = (vis2f ? 1u : 0u) | (sym_ok ? 2u : 0u);

    float4* r = recs + (size_t)idx * 2;
    r[0] = make_float4((float)Apx, (float)Bx, (float)Cx, (float)Apy);
    r[1] = make_float4((float)By, (float)Cy, __uint_as_float(flags), 0.0f);
}

// ---------------------------------------------------------------------------
// Kernel 3: main, 4 adjacent pixels/thread over the PADDED grid.
// One 32B random record (2 dwordx4, same line) per pixel; 4 independent
// gather chains per thread. XCD-chunk swizzled.
// ---------------------------------------------------------------------------
__global__ __launch_bounds__(256) void flow_main_kernel(
    const int*   __restrict__ vis_1,
    const float* __restrict__ vis_sym_mask_1,
    const float4* __restrict__ recs,
    float* __restrict__ out_grid,    // B*H*WP*2 floats
    float* __restrict__ corr_mask)   // B*H*WP floats
{
#pragma clang fp contract(off)
    unsigned bid = blockIdx.x;
    unsigned cpx = gridDim.x >> 3;                 // 8192/8 = 1024
    unsigned swz = (bid & 7u) * cpx + (bid >> 3);
    int tid  = (int)(swz * blockDim.x + threadIdx.x);
    int base = tid * 4;                            // 4 adjacent px
    const int total = B_ * H_ * WP_;
    if (base >= total) return;

    int xp  = base % WP_;          // multiple of 4
    int rem = base / WP_;          // b*H + y
    int y   = rem % H_;
    int b   = rem / H_;

    float4* og4 = reinterpret_cast<float4*>(out_grid);
    float4* cm4 = reinterpret_cast<float4*>(corr_mask);

    if (xp < PAD_ || xp >= W_ + PAD_) {
        og4[(base >> 1) + 0] = make_float4(-1.0f, -1.0f, -1.0f, -1.0f);
        og4[(base >> 1) + 1] = make_float4(-1.0f, -1.0f, -1.0f, -1.0f);
        cm4[base >> 2]       = make_float4(2.0f, 2.0f, 2.0f, 2.0f);
        return;
    }

    int x   = xp - PAD_;
    int pin = (b * H_ + y) * W_ + x;

    int4   vv = *reinterpret_cast<const int4*>(vis_1 + pin);
    float4 mm = *reinterpret_cast<const float4*>(vis_sym_mask_1 + pin);

    int   vis[4] = { vv.x, vv.y, vv.z, vv.w };
    float msk[4] = { mm.x, mm.y, mm.z, mm.w };

    // Issue all 8 record loads up front (4 independent chains).
    float4 R0[4], R1[4];
    bool   bgs[4];
    #pragma unroll
    for (int k = 0; k < 4; ++k) {
        bgs[k] = vis[k] < 0;
        int fc = bgs[k] ? 0 : vis[k];
        const float4* r = recs + ((size_t)b * F_ + fc) * 2;
        R0[k] = r[0];
        R1[k] = r[1];
    }

    float gxo[4], gyo[4], cmo[4];
    #pragma unroll
    for (int k = 0; k < 4; ++k) {
        float Apx = R0[k].x, Bx = R0[k].y, Cx = R0[k].z, Apy = R0[k].w;
        float By  = R1[k].x, Cy = R1[k].y;
        unsigned flags = __float_as_uint(R1[k].z);
        bool vis2f  = (flags & 1u) != 0;
        bool sym_ok = (flags & 2u) != 0;

        float px = (float)(x + k), py = (float)y;

        float corr_x = ((px * Bx) + (py * Cx)) + Apx;
        float corr_y = ((px * By) + (py * Cy)) + Apy;

        bool bg = bgs[k];
        bool use_sym  = (!vis2f) && sym_ok && (msk[k] > 0.0f) && (!bg);
        bool has_corr = (!bg) && (vis2f || use_sym);
        if (!has_corr) { corr_x = 0.0f; corr_y = 0.0f; }

        corr_x = corr_x + (float)PAD_;

        // Replicate flow = corr - base; grid = base + flow (extra roundings).
        float base_x = (float)(xp + k), base_y = py;
        float fx = corr_x - base_x;
        float fy = corr_y - base_y;
        float gxv = base_x + fx;
        float gyv = base_y + fy;

        gxo[k] = ((2.0f * gxv) / (float)(WP_ - 1)) - 1.0f;
        gyo[k] = ((2.0f * gyv) / (float)(H_  - 1)) - 1.0f;
        cmo[k] = bg ? 2.0f : (has_corr ? 0.0f : 1.0f);
    }

    og4[(base >> 1) + 0] = make_float4(gxo[0], gyo[0], gxo[1], gyo[1]);
    og4[(base >> 1) + 1] = make_float4(gxo[2], gyo[2], gxo[3], gyo[3]);
    cm4[base >> 2]       = make_float4(cmo[0], cmo[1], cmo[2], cmo[3]);
}

extern "C" void kernel_launch(void* const* d_in, const int* in_sizes, int n_in,
                              void* d_out, int out_size, void* d_ws, size_t ws_size,
                              hipStream_t stream)
{
    const float* verts_1 = (const float*)d_in[0];
    const int*   vis_1   = (const int*)d_in[1];
    const float* verts_2 = (const float*)d_in[2];
    const int*   vis_2   = (const int*)d_in[3];
    const int*   face    = (const int*)d_in[4];
    const float* vis_sym = (const float*)d_in[5];
    const int*   symtab  = (const int*)d_in[6];

    float* out_grid  = (float*)d_out;                              // B*H*WP*2
    float* corr_mask = (float*)d_out + (size_t)B_ * H_ * WP_ * 2;  // B*H*WP

    // Workspace: [vf2: B*F bytes][align 64][recs: B*F*32 bytes]
    unsigned char* vf2 = (unsigned char*)d_ws;
    size_t rec_off = ((size_t)B_ * F_ + 63) & ~(size_t)63;
    float4* recs = (float4*)((unsigned char*)d_ws + rec_off);

    hipMemsetAsync(vf2, 0, (size_t)B_ * F_, stream);

    {
        const int total4 = B_ * H_ * W_ / 4;          // 1572864
        const int block  = 256;
        const int grid   = total4 / block;            // 6144, %8 == 0
        vf2_scatter_kernel<<<grid, block, 0, stream>>>(
            (const int4*)vis_2, vf2);
    }
    {
        const int total = B_ * F_;                    // 440832 = 1722*256
        const int block = 256;
        face_precompute_kernel<<<(total + block - 1) / block, block, 0, stream>>>(
            verts_1, verts_2, face, symtab, vf2, recs);
    }
    {
        const int total = B_ * H_ * WP_;              // 8388608
        const int block = 256;
        const int grid  = total / (block * 4);        // 8192, %8 == 0
        flow_main_kernel<<<grid, block, 0, stream>>>(
            vis_1, vis_sym, recs, out_grid, corr_mask);
    }
}